// Round 8
// baseline (359.165 us; speedup 1.0000x reference)
//
#include <hip/hip_runtime.h>
#include <cstdint>

#define NEXP 8
#define TOPK 2
#define NTOK 4096
#define NSLOT (NTOK * TOPK)   // 8192
#define CAP 1280              // expert capacity
#define DM 2048               // d_model == hidden
#define EC (NEXP * CAP)       // 10240 binned rows

typedef __bf16 bf16x8 __attribute__((ext_vector_type(8)));
typedef float  f32x4  __attribute__((ext_vector_type(4)));

typedef const void __attribute__((address_space(1))) gvoid;
typedef void __attribute__((address_space(3))) lvoid;

__device__ __forceinline__ void gld16(const void* g, void* l) {
  __builtin_amdgcn_global_load_lds((gvoid*)(uintptr_t)g, (lvoid*)(uintptr_t)l,
                                   16, 0, 0);
}

// pack 4 f32 -> 4 fp8 e4m3 bytes (OCP on gfx950)
__device__ __forceinline__ unsigned fp8x4(float a, float b, float c, float d) {
  int v = __builtin_amdgcn_cvt_pk_fp8_f32(a, b, 0, false);
  v = __builtin_amdgcn_cvt_pk_fp8_f32(c, d, v, true);
  return (unsigned)v;
}
__device__ __forceinline__ unsigned char fp8one(float a) {
  return (unsigned char)(__builtin_amdgcn_cvt_pk_fp8_f32(a, a, 0, false) & 0xff);
}

// ---------------------------------------------------------------- routing
__global__ void route_k(const int* __restrict__ eidx, int* __restrict__ row_token,
                        int* __restrict__ slot_dest, int* __restrict__ mcount,
                        float* __restrict__ out) {
  __shared__ int lh[256][NEXP];
  int tid = threadIdx.x;
  for (int i = tid; i < EC; i += 256) row_token[i] = -1;
#pragma unroll
  for (int e = 0; e < NEXP; ++e) lh[tid][e] = 0;
  __syncthreads();
  int base = tid * 32;
  for (int j = 0; j < 32; ++j) lh[tid][eidx[base + j]]++;
  __syncthreads();
  if (tid < NEXP) {
    int run = 0;
    for (int i = 0; i < 256; ++i) { int t = lh[i][tid]; lh[i][tid] = run; run += t; }
    mcount[tid] = run < CAP ? run : CAP;
    out[(size_t)NTOK * DM + tid] = (float)run;
  }
  __syncthreads();
  for (int j = 0; j < 32; ++j) {
    int t = base + j;
    int e = eidx[t];
    int r = lh[tid][e]++;
    if (r < CAP) { int dst = e * CAP + r; slot_dest[t] = dst; row_token[dst] = t >> 1; }
    else slot_dest[t] = -1;
  }
}

// ------------------------------------------------------- gather + fp32->fp8
__global__ void gather_k(const float* __restrict__ x, const int* __restrict__ row_token,
                         unsigned char* __restrict__ xg) {
  int r = blockIdx.x;
  int c = threadIdx.x * 8;
  int tok = row_token[r];
  uint2 o;
  if (tok >= 0) {
    const float* src = x + (size_t)tok * DM + c;
    float4 a = *(const float4*)src;
    float4 b = *(const float4*)(src + 4);
    o.x = fp8x4(a.x, a.y, a.z, a.w);
    o.y = fp8x4(b.x, b.y, b.z, b.w);
  } else {
    o.x = 0u; o.y = 0u;
  }
  *(uint2*)(xg + (size_t)r * DM + c) = o;
}

// --------------------------------------- fp32 [E][K][N] -> fp8 [E][N][K]
__global__ void transT_k(const float* __restrict__ w, unsigned char* __restrict__ wT) {
  __shared__ float t[64][65];
  int e = blockIdx.z;
  int n0 = blockIdx.x * 64, k0 = blockIdx.y * 64;
  const float* src = w + ((size_t)e << 22) + (size_t)k0 * DM + n0;
  unsigned char* dst = wT + ((size_t)e << 22) + (size_t)n0 * DM + k0;
  int c = threadIdx.x & 63, r4 = threadIdx.x >> 6;
#pragma unroll
  for (int p = 0; p < 16; ++p) {
    int r = p * 4 + r4;
    t[r][c] = src[(size_t)r * DM + c];
  }
  __syncthreads();
  int j = threadIdx.x & 15, rr0 = threadIdx.x >> 4;
#pragma unroll
  for (int q = 0; q < 4; ++q) {
    int rr = q * 16 + rr0;
    unsigned v = fp8x4(t[4 * j + 0][rr], t[4 * j + 1][rr],
                       t[4 * j + 2][rr], t[4 * j + 3][rr]);
    *(unsigned*)(dst + (size_t)rr * DM + 4 * j) = v;   // 4B coalesced stores
  }
}

// ------------------------------------------------------------------- GEMM
// fp8 e4m3, R7 structure + minimal 2-phase pipeline (m248-verified shape):
// 128x128 tile, BK=128, 4 waves (2x2), DOUBLE-buffered LDS (2x32KB), 2
// blocks/CU. Per K-tile: [issue stage(t+1)->buf d^1] [vmcnt(8): waits only
// tile-t loads issued a full tile ago -> ~free] [barrier B1: all waves'
// t-data landed] [compute t from buf d] [barrier B2: buf d readers done
// before t+2's stage (issued after next B1... i.e. after this B2) lands].
// No vmcnt(0) drain until the last tile. MFMA 16x16x32_fp8_fp8, b64 frag
// reads (known 8.9M 2-way-phase conflicts, secondary). Staged with
// inverse-swizzled GLOBAL source + linear LDS dest (rule #21); chunk^(r&7)
// swizzle. XCD-chunked block swizzle (FETCH 197->86MB, R5).
template<bool SWI>
__global__ __launch_bounds__(256, 2)
void gemm_k(const unsigned char* __restrict__ A0, const unsigned char* __restrict__ BT,
            void* C, const __bf16* __restrict__ U, const int* __restrict__ mcount) {
  int lbid = blockIdx.x + 16 * (blockIdx.y + 10 * blockIdx.z);
  int nb = (lbid & 7) * 160 + (lbid >> 3);
  int e = nb / 160, rem = nb % 160, mt = rem >> 4, nt = rem & 15;
  int mc = mcount[e];
  if (mt * 128 >= mc) return;

  __shared__ __align__(16) char smem[64 * 1024];   // A[2][16KB] + B[2][16KB]
  char* lA = smem;                                 // + d*16384
  char* lB = smem + 32768;                         // + d*16384

  int row0 = e * CAP + mt * 128;
  const unsigned char* gA = A0 + (size_t)row0 * DM;
  const unsigned char* gB = BT + ((size_t)e * DM + (size_t)nt * 128) * DM;

  int tid = threadIdx.x, w = tid >> 6, l = tid & 63;
  int wr = w >> 1, wc = w & 1;
  int lr = l & 15, kg = l >> 4;

  int sr = tid >> 3;                 // staging row-in-call (0..31)
  int scs = (tid & 7) ^ (sr & 7);    // inverse-swizzled source chunk

  // one call: 256 lanes x 16B = rows cs*32..cs*32+31 (4KB linear LDS)
  auto stage = [&](int ks, int d) {
#pragma unroll
    for (int cs = 0; cs < 4; ++cs) {
      size_t goff = (size_t)(cs * 32 + sr) * DM + (size_t)ks * 128 + scs * 16;
      gld16(gA + goff, lA + d * 16384 + cs * 4096 + w * 1024);
      gld16(gB + goff, lB + d * 16384 + cs * 4096 + w * 1024);
    }
  };

  f32x4 acc[4][4];
#pragma unroll
  for (int m = 0; m < 4; ++m)
#pragma unroll
    for (int n = 0; n < 4; ++n)
#pragma unroll
      for (int j = 0; j < 4; ++j) acc[m][n][j] = 0.f;

  stage(0, 0);                               // 8 loads outstanding

#pragma unroll 1
  for (int ks = 0; ks < 16; ++ks) {          // K = 2048 = 16 * 128
    int d = ks & 1;
    if (ks + 1 < 16) {
      stage(ks + 1, d ^ 1);                  // +8 -> 16 outstanding
      asm volatile("s_waitcnt vmcnt(8)" ::: "memory");   // t's 8 landed (~free)
    } else {
      asm volatile("s_waitcnt vmcnt(0)" ::: "memory");
    }
    __builtin_amdgcn_s_barrier();            // B1: all waves' tile-t data in LDS

    // ---- 4 K-slabs of 32: 8 b64 frag reads + 16 MFMA each
#pragma unroll
    for (int kk = 0; kk < 4; ++kk) {
      int chunk = kk * 2 + (kg >> 1);
      int ho = (kg & 1) << 3;
      long af[4], bf[4];
#pragma unroll
      for (int m = 0; m < 4; ++m) {
        int r = wr * 64 + m * 16 + lr;
        af[m] = *(const long*)(lA + d * 16384 + r * 128 + ((chunk ^ (r & 7)) << 4) + ho);
      }
#pragma unroll
      for (int n = 0; n < 4; ++n) {
        int r = wc * 64 + n * 16 + lr;
        bf[n] = *(const long*)(lB + d * 16384 + r * 128 + ((chunk ^ (r & 7)) << 4) + ho);
      }
#pragma unroll
      for (int m = 0; m < 4; ++m)
#pragma unroll
        for (int n = 0; n < 4; ++n)
          acc[m][n] = __builtin_amdgcn_mfma_f32_16x16x32_fp8_fp8(af[m], bf[n],
                                                                 acc[m][n], 0, 0, 0);
    }
    __builtin_amdgcn_s_barrier();            // B2: buf d readers done
  }

  // ---- epilogue: C/D layout col=lane&15, row=(lane>>4)*4+j [m89-verified]
  int rg = l >> 4;
#pragma unroll
  for (int m = 0; m < 4; ++m)
#pragma unroll
    for (int n = 0; n < 4; ++n)
#pragma unroll
      for (int j = 0; j < 4; ++j) {
        int rr = row0 + wr * 64 + m * 16 + rg * 4 + j;
        int cc = nt * 128 + wc * 64 + n * 16 + lr;
        size_t off = (size_t)rr * DM + cc;
        float v = acc[m][n][j];
        if constexpr (SWI) {
          float u = (float)U[off];
          float s = u / (1.f + __expf(-u));
          ((unsigned char*)C)[off] = fp8one(s * v);  // h = silu(u)*v, fp8
        } else {
          ((__bf16*)C)[off] = (__bf16)v;
        }
      }
}

// --------------------------------------------- combine: y[tok] = sum w * ye
__global__ void combine_k(const __bf16* __restrict__ ye, const int* __restrict__ slot_dest,
                          const float* __restrict__ ew, float* __restrict__ out) {
  int tok = blockIdx.x;
  int c = threadIdx.x * 8;
  int d0 = slot_dest[2 * tok], d1 = slot_dest[2 * tok + 1];
  float w0 = ew[2 * tok], w1 = ew[2 * tok + 1];
  float r[8];
#pragma unroll
  for (int j = 0; j < 8; ++j) r[j] = 0.f;
  if (d0 >= 0) {
    bf16x8 y0 = *(const bf16x8*)(ye + (size_t)d0 * DM + c);
#pragma unroll
    for (int j = 0; j < 8; ++j) r[j] += w0 * (float)y0[j];
  }
  if (d1 >= 0) {
    bf16x8 y1 = *(const bf16x8*)(ye + (size_t)d1 * DM + c);
#pragma unroll
    for (int j = 0; j < 8; ++j) r[j] += w1 * (float)y1[j];
  }
  float* dst = out + (size_t)tok * DM + c;
  float4 o0; o0.x = r[0]; o0.y = r[1]; o0.z = r[2]; o0.w = r[3];
  float4 o1; o1.x = r[4]; o1.y = r[5]; o1.z = r[6]; o1.w = r[7];
  *(float4*)dst = o0;
  *(float4*)(dst + 4) = o1;
}

extern "C" void kernel_launch(void* const* d_in, const int* in_sizes, int n_in,
                              void* d_out, int out_size, void* d_ws, size_t ws_size,
                              hipStream_t stream) {
  const float* x  = (const float*)d_in[0];
  const float* ew = (const float*)d_in[1];
  const int*   ei = (const int*)d_in[2];
  const float* w1 = (const float*)d_in[3];
  const float* w2 = (const float*)d_in[4];
  const float* w3 = (const float*)d_in[5];
  float* out = (float*)d_out;
  char* ws = (char*)d_ws;

  // ws: xg fp8 (21MB) | uB bf16 (42MB: u, then ye) | hB fp8 (21MB) |
  //     wT fp8 (33.5MB, reused 3x) | routing ints       (~118MB total)
  const size_t SZ8  = (size_t)EC * DM;                  // 20,971,520
  const size_t SZ16 = 2 * SZ8;                          // 41,943,040
  unsigned char* xg = (unsigned char*)ws;
  __bf16* uB = (__bf16*)(ws + SZ8);                     // u, then ye
  unsigned char* hB = (unsigned char*)(ws + SZ8 + SZ16);
  unsigned char* wT = (unsigned char*)(ws + 2 * SZ8 + SZ16);
  char* ints = ws + 2 * SZ8 + SZ16 + (size_t)NEXP * DM * DM;
  int* row_token = (int*)ints;
  int* slot_dest = row_token + EC;
  int* mcount    = slot_dest + NSLOT;

  dim3 tgrid(32, 32, NEXP);
  dim3 ggrid(16, 10, NEXP);                             // nt(128), mt(128), e

  route_k<<<1, 256, 0, stream>>>(ei, row_token, slot_dest, mcount, out);
  gather_k<<<EC, 256, 0, stream>>>(x, row_token, xg);

  transT_k<<<tgrid, 256, 0, stream>>>(w1, wT);
  gemm_k<false><<<ggrid, 256, 0, stream>>>(xg, wT, uB, nullptr, mcount); // u (bf16)

  transT_k<<<tgrid, 256, 0, stream>>>(w3, wT);
  gemm_k<true><<<ggrid, 256, 0, stream>>>(xg, wT, hB, uB, mcount);       // h (fp8)

  transT_k<<<tgrid, 256, 0, stream>>>(w2, wT);
  gemm_k<false><<<ggrid, 256, 0, stream>>>(hB, wT, uB, nullptr, mcount); // ye (bf16)

  combine_k<<<NTOK, 256, 0, stream>>>(uB, slot_dest, ew, out);
}

// Round 9
// 330.805 us; speedup vs baseline: 1.0857x; 1.0857x over previous
//
#include <hip/hip_runtime.h>
#include <cstdint>

#define NEXP 8
#define TOPK 2
#define NTOK 4096
#define NSLOT (NTOK * TOPK)   // 8192
#define CAP 1280              // expert capacity
#define DM 2048               // d_model == hidden
#define EC (NEXP * CAP)       // 10240 binned rows

typedef __bf16 bf16x8 __attribute__((ext_vector_type(8)));
typedef float  f32x16 __attribute__((ext_vector_type(16)));
typedef int    i32x4  __attribute__((ext_vector_type(4)));
typedef int    i32x8  __attribute__((ext_vector_type(8)));

typedef const void __attribute__((address_space(1))) gvoid;
typedef void __attribute__((address_space(3))) lvoid;

__device__ __forceinline__ void gld16(const void* g, void* l) {
  __builtin_amdgcn_global_load_lds((gvoid*)(uintptr_t)g, (lvoid*)(uintptr_t)l,
                                   16, 0, 0);
}

// pack 4 f32 -> 4 fp8 e4m3 bytes (OCP on gfx950)
__device__ __forceinline__ unsigned fp8x4(float a, float b, float c, float d) {
  int v = __builtin_amdgcn_cvt_pk_fp8_f32(a, b, 0, false);
  v = __builtin_amdgcn_cvt_pk_fp8_f32(c, d, v, true);
  return (unsigned)v;
}
__device__ __forceinline__ unsigned char fp8one(float a) {
  return (unsigned char)(__builtin_amdgcn_cvt_pk_fp8_f32(a, a, 0, false) & 0xff);
}

// ---------------------------------------------------------------- routing
__global__ void route_k(const int* __restrict__ eidx, int* __restrict__ row_token,
                        int* __restrict__ slot_dest, int* __restrict__ mcount,
                        float* __restrict__ out) {
  __shared__ int lh[256][NEXP];
  int tid = threadIdx.x;
  for (int i = tid; i < EC; i += 256) row_token[i] = -1;
#pragma unroll
  for (int e = 0; e < NEXP; ++e) lh[tid][e] = 0;
  __syncthreads();
  int base = tid * 32;
  for (int j = 0; j < 32; ++j) lh[tid][eidx[base + j]]++;
  __syncthreads();
  if (tid < NEXP) {
    int run = 0;
    for (int i = 0; i < 256; ++i) { int t = lh[i][tid]; lh[i][tid] = run; run += t; }
    mcount[tid] = run < CAP ? run : CAP;
    out[(size_t)NTOK * DM + tid] = (float)run;
  }
  __syncthreads();
  for (int j = 0; j < 32; ++j) {
    int t = base + j;
    int e = eidx[t];
    int r = lh[tid][e]++;
    if (r < CAP) { int dst = e * CAP + r; slot_dest[t] = dst; row_token[dst] = t >> 1; }
    else slot_dest[t] = -1;
  }
}

// ------------------------------------------------------- gather + fp32->fp8
__global__ void gather_k(const float* __restrict__ x, const int* __restrict__ row_token,
                         unsigned char* __restrict__ xg) {
  int r = blockIdx.x;
  int c = threadIdx.x * 8;
  int tok = row_token[r];
  uint2 o;
  if (tok >= 0) {
    const float* src = x + (size_t)tok * DM + c;
    float4 a = *(const float4*)src;
    float4 b = *(const float4*)(src + 4);
    o.x = fp8x4(a.x, a.y, a.z, a.w);
    o.y = fp8x4(b.x, b.y, b.z, b.w);
  } else {
    o.x = 0u; o.y = 0u;
  }
  *(uint2*)(xg + (size_t)r * DM + c) = o;
}

// --------------------------------------- fp32 [E][K][N] -> fp8 [E][N][K]
__global__ void transT_k(const float* __restrict__ w, unsigned char* __restrict__ wT) {
  __shared__ float t[64][65];
  int e = blockIdx.z;
  int n0 = blockIdx.x * 64, k0 = blockIdx.y * 64;
  const float* src = w + ((size_t)e << 22) + (size_t)k0 * DM + n0;
  unsigned char* dst = wT + ((size_t)e << 22) + (size_t)n0 * DM + k0;
  int c = threadIdx.x & 63, r4 = threadIdx.x >> 6;
#pragma unroll
  for (int p = 0; p < 16; ++p) {
    int r = p * 4 + r4;
    t[r][c] = src[(size_t)r * DM + c];
  }
  __syncthreads();
  int j = threadIdx.x & 15, rr0 = threadIdx.x >> 4;
#pragma unroll
  for (int q = 0; q < 4; ++q) {
    int rr = q * 16 + rr0;
    unsigned v = fp8x4(t[4 * j + 0][rr], t[4 * j + 1][rr],
                       t[4 * j + 2][rr], t[4 * j + 3][rr]);
    *(unsigned*)(dst + (size_t)rr * DM + 4 * j) = v;   // 4B coalesced stores
  }
}

// ------------------------------------------------------------------- GEMM
// MX-fp8 (unit scales) on the R7-proven single-buffer structure:
// 128x128 tile, BK=256 (rows = 256B fp8), 4 waves (2x2), per-wave 64x64 via
// 2x2 of 32x32 MFMA. mfma_scale_f32_32x32x64_f8f6f4, fmt=0 (e4m3), scale
// 0x7F = 1.0 both sides -> plain fp8 GEMM at 2x rate (m148: 995->1628 TF on
// this same structure). K-byte permutation per lane cancels between A and B
// (identical addressing both sides); C/D layout = m74/m101-verified 32x32
// mapping (shape-determined, m121). 8 K-iters (barriers halved vs R7).
// LDS 64KB single buffer, 2 blocks/CU (cross-block overlap does the latency
// hiding; 4/4 explicit-pipeline attempts regressed - structure locked).
// Swizzle: LDS[row][chunk] holds global chunk^(row&15); frag reads b128 at
// chunk cg^(r&15): within every 16-lane group rows span 16 -> distinct slots,
// 2-way start-bank aliasing only = free (m136). Staged with inverse-swizzled
// GLOBAL source + linear LDS dest (rule #21). XCD-chunked block swizzle (R5).
template<bool SWI>
__global__ __launch_bounds__(256, 2)
void gemm_k(const unsigned char* __restrict__ A0, const unsigned char* __restrict__ BT,
            void* C, const __bf16* __restrict__ U, const int* __restrict__ mcount) {
  int lbid = blockIdx.x + 16 * (blockIdx.y + 10 * blockIdx.z);
  int nb = (lbid & 7) * 160 + (lbid >> 3);
  int e = nb / 160, rem = nb % 160, mt = rem >> 4, nt = rem & 15;
  int mc = mcount[e];
  if (mt * 128 >= mc) return;

  __shared__ __align__(16) char smem[64 * 1024];   // A 32KB + B 32KB
  char* lA = smem;
  char* lB = smem + 32768;

  int row0 = e * CAP + mt * 128;
  const unsigned char* gA = A0 + (size_t)row0 * DM;
  const unsigned char* gB = BT + ((size_t)e * DM + (size_t)nt * 128) * DM;

  int tid = threadIdx.x, w = tid >> 6, l = tid & 63;
  int wr = w >> 1, wc = w & 1;
  int cl = l & 31, kb = l >> 5;      // MFMA: row/col = l&31, k-block = l>>5

  int sr = tid >> 4;                 // staging row-in-call (0..15)
  int scs = (tid & 15) ^ sr;         // inverse-swizzled source chunk (r&15==sr)

  f32x16 acc[2][2];
#pragma unroll
  for (int m = 0; m < 2; ++m)
#pragma unroll
    for (int n = 0; n < 2; ++n)
#pragma unroll
      for (int j = 0; j < 16; ++j) acc[m][n][j] = 0.f;

  // frag read: rows base R, kstep s, 32B/lane as 2 x b128
  auto rdfrag = [&](const char* lX, int R, int s) -> i32x8 {
    int r = R + cl;
    int cg = s * 4 + kb * 2;
    int a0 = r * 256 + (((cg + 0) ^ (r & 15)) << 4);
    int a1 = r * 256 + (((cg + 1) ^ (r & 15)) << 4);
    i32x4 lo = *(const i32x4*)(lX + a0);
    i32x4 hi = *(const i32x4*)(lX + a1);
    i32x8 v;
    v[0] = lo[0]; v[1] = lo[1]; v[2] = lo[2]; v[3] = lo[3];
    v[4] = hi[0]; v[5] = hi[1]; v[6] = hi[2]; v[7] = hi[3];
    return v;
  };

#pragma unroll 1
  for (int ks = 0; ks < 8; ++ks) {           // K = 2048 = 8 * 256
    // ---- stage A and B tiles: 128 rows x 256B each; 8 calls per matrix
    //      (call s: rows s*16..s*16+15; 256 lanes x 16B = 4KB linear LDS)
#pragma unroll
    for (int s = 0; s < 8; ++s) {
      size_t goff = (size_t)(s * 16 + sr) * DM + (size_t)ks * 256 + scs * 16;
      gld16(gA + goff, lA + s * 4096 + w * 1024);
      gld16(gB + goff, lB + s * 4096 + w * 1024);
    }
    __syncthreads();
    // ---- 4 k-steps of 64: 8 b128-pair frag reads + 4 MFMA each
#pragma unroll
    for (int s = 0; s < 4; ++s) {
      i32x8 af[2], bf[2];
#pragma unroll
      for (int m = 0; m < 2; ++m) af[m] = rdfrag(lA, wr * 64 + m * 32, s);
#pragma unroll
      for (int n = 0; n < 2; ++n) bf[n] = rdfrag(lB, wc * 64 + n * 32, s);
#pragma unroll
      for (int m = 0; m < 2; ++m)
#pragma unroll
        for (int n = 0; n < 2; ++n)
          acc[m][n] = __builtin_amdgcn_mfma_scale_f32_32x32x64_f8f6f4(
              af[m], bf[n], acc[m][n], 0, 0, 0, 0x7F, 0, 0x7F);
    }
    __syncthreads();
  }

  // ---- epilogue: 32x32 C/D layout col=lane&31, row=(q&3)+8*(q>>2)+4*(l>>5)
  //      [m74/m101-verified; shape-determined per m121]
#pragma unroll
  for (int m = 0; m < 2; ++m)
#pragma unroll
    for (int n = 0; n < 2; ++n)
#pragma unroll
      for (int q = 0; q < 16; ++q) {
        int rr = row0 + wr * 64 + m * 32 + (q & 3) + 8 * (q >> 2) + 4 * kb;
        int cc = nt * 128 + wc * 64 + n * 32 + cl;
        size_t off = (size_t)rr * DM + cc;
        float v = acc[m][n][q];
        if constexpr (SWI) {
          float u = (float)U[off];
          float s = u / (1.f + __expf(-u));
          ((unsigned char*)C)[off] = fp8one(s * v);  // h = silu(u)*v, fp8
        } else {
          ((__bf16*)C)[off] = (__bf16)v;
        }
      }
}

// --------------------------------------------- combine: y[tok] = sum w * ye
__global__ void combine_k(const __bf16* __restrict__ ye, const int* __restrict__ slot_dest,
                          const float* __restrict__ ew, float* __restrict__ out) {
  int tok = blockIdx.x;
  int c = threadIdx.x * 8;
  int d0 = slot_dest[2 * tok], d1 = slot_dest[2 * tok + 1];
  float w0 = ew[2 * tok], w1 = ew[2 * tok + 1];
  float r[8];
#pragma unroll
  for (int j = 0; j < 8; ++j) r[j] = 0.f;
  if (d0 >= 0) {
    bf16x8 y0 = *(const bf16x8*)(ye + (size_t)d0 * DM + c);
#pragma unroll
    for (int j = 0; j < 8; ++j) r[j] += w0 * (float)y0[j];
  }
  if (d1 >= 0) {
    bf16x8 y1 = *(const bf16x8*)(ye + (size_t)d1 * DM + c);
#pragma unroll
    for (int j = 0; j < 8; ++j) r[j] += w1 * (float)y1[j];
  }
  float* dst = out + (size_t)tok * DM + c;
  float4 o0; o0.x = r[0]; o0.y = r[1]; o0.z = r[2]; o0.w = r[3];
  float4 o1; o1.x = r[4]; o1.y = r[5]; o1.z = r[6]; o1.w = r[7];
  *(float4*)dst = o0;
  *(float4*)(dst + 4) = o1;
}

extern "C" void kernel_launch(void* const* d_in, const int* in_sizes, int n_in,
                              void* d_out, int out_size, void* d_ws, size_t ws_size,
                              hipStream_t stream) {
  const float* x  = (const float*)d_in[0];
  const float* ew = (const float*)d_in[1];
  const int*   ei = (const int*)d_in[2];
  const float* w1 = (const float*)d_in[3];
  const float* w2 = (const float*)d_in[4];
  const float* w3 = (const float*)d_in[5];
  float* out = (float*)d_out;
  char* ws = (char*)d_ws;

  // ws: xg fp8 (21MB) | uB bf16 (42MB: u, then ye) | hB fp8 (21MB) |
  //     wT fp8 (33.5MB, reused 3x) | routing ints       (~118MB total)
  const size_t SZ8  = (size_t)EC * DM;                  // 20,971,520
  const size_t SZ16 = 2 * SZ8;                          // 41,943,040
  unsigned char* xg = (unsigned char*)ws;
  __bf16* uB = (__bf16*)(ws + SZ8);                     // u, then ye
  unsigned char* hB = (unsigned char*)(ws + SZ8 + SZ16);
  unsigned char* wT = (unsigned char*)(ws + 2 * SZ8 + SZ16);
  char* ints = ws + 2 * SZ8 + SZ16 + (size_t)NEXP * DM * DM;
  int* row_token = (int*)ints;
  int* slot_dest = row_token + EC;
  int* mcount    = slot_dest + NSLOT;

  dim3 tgrid(32, 32, NEXP);
  dim3 ggrid(16, 10, NEXP);                             // nt(128), mt(128), e

  route_k<<<1, 256, 0, stream>>>(ei, row_token, slot_dest, mcount, out);
  gather_k<<<EC, 256, 0, stream>>>(x, row_token, xg);

  transT_k<<<tgrid, 256, 0, stream>>>(w1, wT);
  gemm_k<false><<<ggrid, 256, 0, stream>>>(xg, wT, uB, nullptr, mcount); // u (bf16)

  transT_k<<<tgrid, 256, 0, stream>>>(w3, wT);
  gemm_k<true><<<ggrid, 256, 0, stream>>>(xg, wT, hB, uB, mcount);       // h (fp8)

  transT_k<<<tgrid, 256, 0, stream>>>(w2, wT);
  gemm_k<false><<<ggrid, 256, 0, stream>>>(hB, wT, uB, nullptr, mcount); // ye (bf16)

  combine_k<<<NTOK, 256, 0, stream>>>(uB, slot_dest, ew, out);
}

// Round 10
// 315.825 us; speedup vs baseline: 1.1372x; 1.0474x over previous
//
#include <hip/hip_runtime.h>
#include <cstdint>

#define NEXP 8
#define TOPK 2
#define NTOK 4096
#define NSLOT (NTOK * TOPK)   // 8192
#define CAP 1280              // expert capacity
#define DM 2048               // d_model == hidden
#define EC (NEXP * CAP)       // 10240 binned rows

typedef __bf16 bf16x8 __attribute__((ext_vector_type(8)));
typedef float  f32x4  __attribute__((ext_vector_type(4)));
typedef int    i32x4  __attribute__((ext_vector_type(4)));
typedef int    i32x8  __attribute__((ext_vector_type(8)));

typedef const void __attribute__((address_space(1))) gvoid;
typedef void __attribute__((address_space(3))) lvoid;

__device__ __forceinline__ void gld16(const void* g, void* l) {
  __builtin_amdgcn_global_load_lds((gvoid*)(uintptr_t)g, (lvoid*)(uintptr_t)l,
                                   16, 0, 0);
}

// pack 4 f32 -> 4 fp8 e4m3 bytes (OCP on gfx950)
__device__ __forceinline__ unsigned fp8x4(float a, float b, float c, float d) {
  int v = __builtin_amdgcn_cvt_pk_fp8_f32(a, b, 0, false);
  v = __builtin_amdgcn_cvt_pk_fp8_f32(c, d, v, true);
  return (unsigned)v;
}
__device__ __forceinline__ unsigned char fp8one(float a) {
  return (unsigned char)(__builtin_amdgcn_cvt_pk_fp8_f32(a, a, 0, false) & 0xff);
}

// ---------------------------------------------------------------- routing
__global__ void route_k(const int* __restrict__ eidx, int* __restrict__ row_token,
                        int* __restrict__ slot_dest, int* __restrict__ mcount,
                        float* __restrict__ out) {
  __shared__ int lh[256][NEXP];
  int tid = threadIdx.x;
  for (int i = tid; i < EC; i += 256) row_token[i] = -1;
#pragma unroll
  for (int e = 0; e < NEXP; ++e) lh[tid][e] = 0;
  __syncthreads();
  int base = tid * 32;
  for (int j = 0; j < 32; ++j) lh[tid][eidx[base + j]]++;
  __syncthreads();
  if (tid < NEXP) {
    int run = 0;
    for (int i = 0; i < 256; ++i) { int t = lh[i][tid]; lh[i][tid] = run; run += t; }
    mcount[tid] = run < CAP ? run : CAP;
    out[(size_t)NTOK * DM + tid] = (float)run;
  }
  __syncthreads();
  for (int j = 0; j < 32; ++j) {
    int t = base + j;
    int e = eidx[t];
    int r = lh[tid][e]++;
    if (r < CAP) { int dst = e * CAP + r; slot_dest[t] = dst; row_token[dst] = t >> 1; }
    else slot_dest[t] = -1;
  }
}

// ------------------------------------------------------- gather + fp32->fp8
__global__ void gather_k(const float* __restrict__ x, const int* __restrict__ row_token,
                         unsigned char* __restrict__ xg) {
  int r = blockIdx.x;
  int c = threadIdx.x * 8;
  int tok = row_token[r];
  uint2 o;
  if (tok >= 0) {
    const float* src = x + (size_t)tok * DM + c;
    float4 a = *(const float4*)src;
    float4 b = *(const float4*)(src + 4);
    o.x = fp8x4(a.x, a.y, a.z, a.w);
    o.y = fp8x4(b.x, b.y, b.z, b.w);
  } else {
    o.x = 0u; o.y = 0u;
  }
  *(uint2*)(xg + (size_t)r * DM + c) = o;
}

// --------------------------------------- fp32 [E][K][N] -> fp8 [E][N][K]
// float4 global loads (G13), f32 LDS tile pad 69 (8*69%32=8 -> j-lanes
// spread banks; scalar LDS stores keep float4 alignment irrelevant),
// 8B packed fp8 stores.
__global__ void transT_k(const float* __restrict__ w, unsigned char* __restrict__ wT) {
  __shared__ float t[64][69];
  int e = blockIdx.z;
  int n0 = blockIdx.x * 64, k0 = blockIdx.y * 64;
  const float* src = w + ((size_t)e << 22) + (size_t)k0 * DM + n0;
  unsigned char* dst = wT + ((size_t)e << 22) + (size_t)n0 * DM + k0;
  int c4 = (threadIdx.x & 15) * 4, r0 = threadIdx.x >> 4;   // 16 rows/sweep
#pragma unroll
  for (int p = 0; p < 4; ++p) {
    int r = p * 16 + r0;
    float4 v = *(const float4*)(src + (size_t)r * DM + c4);
    t[r][c4 + 0] = v.x; t[r][c4 + 1] = v.y; t[r][c4 + 2] = v.z; t[r][c4 + 3] = v.w;
  }
  __syncthreads();
  int j = threadIdx.x & 7, rr0 = threadIdx.x >> 3;          // 32 rows/sweep
#pragma unroll
  for (int q = 0; q < 2; ++q) {
    int rr = q * 32 + rr0;
    int k8 = j * 8;
    uint2 v;
    v.x = fp8x4(t[k8 + 0][rr], t[k8 + 1][rr], t[k8 + 2][rr], t[k8 + 3][rr]);
    v.y = fp8x4(t[k8 + 4][rr], t[k8 + 5][rr], t[k8 + 6][rr], t[k8 + 7][rr]);
    *(uint2*)(dst + (size_t)rr * DM + k8) = v;              // 8B stores
  }
}

// ------------------------------------------------------------------- GEMM
// MX-fp8 (unit scales) via mfma_scale_f32_16x16x128_f8f6f4 on the R7-proven
// occupancy shape: 128x128 tile, BK=128, 4 waves (2x2), 32KB single-buffer
// LDS, 4+ blocks/CU (cross-block overlap does the latency hiding; 4/4
// explicit-pipeline attempts regressed - structure locked). K=128/instr ->
// 16 MFMA per wave per tile, 16 K-iters. Frag = 2 x b128 at chunks
// (2ks)^(r&7),(2ks+1)^(r&7), 16-row groups -> rows r,r+8 2-way alias = free
// (m136); kills R7's b64 half-offset conflicts. Per-lane K mapping need not
// match HW docs: A and B use identical addressing so any lane/K bijection
// cancels in the contraction (R9-refcheck-proven argument). C/D = 16x16 m89
// layout (shape-determined, m121). Staged with inverse-swizzled GLOBAL
// source + linear LDS dest (rule #21). XCD-chunked block swizzle (R5).
template<bool SWI>
__global__ __launch_bounds__(256, 4)
void gemm_k(const unsigned char* __restrict__ A0, const unsigned char* __restrict__ BT,
            void* C, const __bf16* __restrict__ U, const int* __restrict__ mcount) {
  int lbid = blockIdx.x + 16 * (blockIdx.y + 10 * blockIdx.z);
  int nb = (lbid & 7) * 160 + (lbid >> 3);
  int e = nb / 160, rem = nb % 160, mt = rem >> 4, nt = rem & 15;
  int mc = mcount[e];
  if (mt * 128 >= mc) return;

  __shared__ __align__(16) char smem[32 * 1024];   // A 16KB + B 16KB
  char* lA = smem;
  char* lB = smem + 16384;

  int row0 = e * CAP + mt * 128;
  const unsigned char* gA = A0 + (size_t)row0 * DM;
  const unsigned char* gB = BT + ((size_t)e * DM + (size_t)nt * 128) * DM;

  int tid = threadIdx.x, w = tid >> 6, l = tid & 63;
  int wr = w >> 1, wc = w & 1;
  int lr = l & 15, kg = l >> 4;      // MFMA 16x16: row=l&15, kslice=l>>4

  int sr = tid >> 3;                 // staging row-in-call (0..31)
  int scs = (tid & 7) ^ (sr & 7);    // inverse-swizzled source chunk

  f32x4 acc[4][4];
#pragma unroll
  for (int m = 0; m < 4; ++m)
#pragma unroll
    for (int n = 0; n < 4; ++n)
#pragma unroll
      for (int j = 0; j < 4; ++j) acc[m][n][j] = 0.f;

  // frag read: row base R; lane reads 32 K-bytes = 2 swizzled b128
  auto rdfrag = [&](const char* lX, int R) -> i32x8 {
    int r = R + lr;
    int a0 = r * 128 + (((2 * kg + 0) ^ (r & 7)) << 4);
    int a1 = r * 128 + (((2 * kg + 1) ^ (r & 7)) << 4);
    i32x4 lo = *(const i32x4*)(lX + a0);
    i32x4 hi = *(const i32x4*)(lX + a1);
    i32x8 v;
    v[0] = lo[0]; v[1] = lo[1]; v[2] = lo[2]; v[3] = lo[3];
    v[4] = hi[0]; v[5] = hi[1]; v[6] = hi[2]; v[7] = hi[3];
    return v;
  };

#pragma unroll 1
  for (int ks = 0; ks < 16; ++ks) {          // K = 2048 = 16 * 128
    // ---- stage A and B tiles: 128 rows x 128B each; 4 calls per matrix
    //      (call s: rows s*32..s*32+31; 256 lanes x 16B = 4KB linear LDS)
#pragma unroll
    for (int s = 0; s < 4; ++s) {
      size_t goff = (size_t)(s * 32 + sr) * DM + (size_t)ks * 128 + scs * 16;
      gld16(gA + goff, lA + s * 4096 + w * 1024);
      gld16(gB + goff, lB + s * 4096 + w * 1024);
    }
    __syncthreads();
    // ---- 16 MFMA (full K=128 each): bf[4] up front, af per-m (reg pressure)
    i32x8 bf[4];
#pragma unroll
    for (int n = 0; n < 4; ++n) bf[n] = rdfrag(lB, wc * 64 + n * 16);
#pragma unroll
    for (int m = 0; m < 4; ++m) {
      i32x8 af = rdfrag(lA, wr * 64 + m * 16);
#pragma unroll
      for (int n = 0; n < 4; ++n)
        acc[m][n] = __builtin_amdgcn_mfma_scale_f32_16x16x128_f8f6f4(
            af, bf[n], acc[m][n], 0, 0, 0, 0x7F, 0, 0x7F);
    }
    __syncthreads();
  }

  // ---- epilogue: C/D layout col=lane&15, row=(lane>>4)*4+j [m89-verified]
  int rg = l >> 4;
#pragma unroll
  for (int m = 0; m < 4; ++m)
#pragma unroll
    for (int n = 0; n < 4; ++n)
#pragma unroll
      for (int j = 0; j < 4; ++j) {
        int rr = row0 + wr * 64 + m * 16 + rg * 4 + j;
        int cc = nt * 128 + wc * 64 + n * 16 + lr;
        size_t off = (size_t)rr * DM + cc;
        float v = acc[m][n][j];
        if constexpr (SWI) {
          float u = (float)U[off];
          float s = u / (1.f + __expf(-u));
          ((unsigned char*)C)[off] = fp8one(s * v);  // h = silu(u)*v, fp8
        } else {
          ((__bf16*)C)[off] = (__bf16)v;
        }
      }
}

// --------------------------------------------- combine: y[tok] = sum w * ye
__global__ void combine_k(const __bf16* __restrict__ ye, const int* __restrict__ slot_dest,
                          const float* __restrict__ ew, float* __restrict__ out) {
  int tok = blockIdx.x;
  int c = threadIdx.x * 8;
  int d0 = slot_dest[2 * tok], d1 = slot_dest[2 * tok + 1];
  float w0 = ew[2 * tok], w1 = ew[2 * tok + 1];
  float r[8];
#pragma unroll
  for (int j = 0; j < 8; ++j) r[j] = 0.f;
  if (d0 >= 0) {
    bf16x8 y0 = *(const bf16x8*)(ye + (size_t)d0 * DM + c);
#pragma unroll
    for (int j = 0; j < 8; ++j) r[j] += w0 * (float)y0[j];
  }
  if (d1 >= 0) {
    bf16x8 y1 = *(const bf16x8*)(ye + (size_t)d1 * DM + c);
#pragma unroll
    for (int j = 0; j < 8; ++j) r[j] += w1 * (float)y1[j];
  }
  float* dst = out + (size_t)tok * DM + c;
  float4 o0; o0.x = r[0]; o0.y = r[1]; o0.z = r[2]; o0.w = r[3];
  float4 o1; o1.x = r[4]; o1.y = r[5]; o1.z = r[6]; o1.w = r[7];
  *(float4*)dst = o0;
  *(float4*)(dst + 4) = o1;
}

extern "C" void kernel_launch(void* const* d_in, const int* in_sizes, int n_in,
                              void* d_out, int out_size, void* d_ws, size_t ws_size,
                              hipStream_t stream) {
  const float* x  = (const float*)d_in[0];
  const float* ew = (const float*)d_in[1];
  const int*   ei = (const int*)d_in[2];
  const float* w1 = (const float*)d_in[3];
  const float* w2 = (const float*)d_in[4];
  const float* w3 = (const float*)d_in[5];
  float* out = (float*)d_out;
  char* ws = (char*)d_ws;

  // ws: xg fp8 (21MB) | uB bf16 (42MB: u, then ye) | hB fp8 (21MB) |
  //     wT fp8 (33.5MB, reused 3x) | routing ints       (~118MB total)
  const size_t SZ8  = (size_t)EC * DM;                  // 20,971,520
  const size_t SZ16 = 2 * SZ8;                          // 41,943,040
  unsigned char* xg = (unsigned char*)ws;
  __bf16* uB = (__bf16*)(ws + SZ8);                     // u, then ye
  unsigned char* hB = (unsigned char*)(ws + SZ8 + SZ16);
  unsigned char* wT = (unsigned char*)(ws + 2 * SZ8 + SZ16);
  char* ints = ws + 2 * SZ8 + SZ16 + (size_t)NEXP * DM * DM;
  int* row_token = (int*)ints;
  int* slot_dest = row_token + EC;
  int* mcount    = slot_dest + NSLOT;

  dim3 tgrid(32, 32, NEXP);
  dim3 ggrid(16, 10, NEXP);                             // nt(128), mt(128), e

  route_k<<<1, 256, 0, stream>>>(ei, row_token, slot_dest, mcount, out);
  gather_k<<<EC, 256, 0, stream>>>(x, row_token, xg);

  transT_k<<<tgrid, 256, 0, stream>>>(w1, wT);
  gemm_k<false><<<ggrid, 256, 0, stream>>>(xg, wT, uB, nullptr, mcount); // u (bf16)

  transT_k<<<tgrid, 256, 0, stream>>>(w3, wT);
  gemm_k<true><<<ggrid, 256, 0, stream>>>(xg, wT, hB, uB, mcount);       // h (fp8)

  transT_k<<<tgrid, 256, 0, stream>>>(w2, wT);
  gemm_k<false><<<ggrid, 256, 0, stream>>>(hB, wT, uB, nullptr, mcount); // ye (bf16)

  combine_k<<<NTOK, 256, 0, stream>>>(uB, slot_dest, ew, out);
}

// Round 11
// 303.615 us; speedup vs baseline: 1.1830x; 1.0402x over previous
//
#include <hip/hip_runtime.h>
#include <cstdint>

#define NEXP 8
#define TOPK 2
#define NTOK 4096
#define NSLOT (NTOK * TOPK)   // 8192
#define CAP 1280              // expert capacity
#define DM 2048               // d_model == hidden
#define EC (NEXP * CAP)       // 10240 binned rows

typedef __bf16 bf16x8 __attribute__((ext_vector_type(8)));
typedef float  f32x4  __attribute__((ext_vector_type(4)));
typedef int    i32x4  __attribute__((ext_vector_type(4)));
typedef int    i32x8  __attribute__((ext_vector_type(8)));

typedef const void __attribute__((address_space(1))) gvoid;
typedef void __attribute__((address_space(3))) lvoid;

__device__ __forceinline__ void gld16(const void* g, void* l) {
  __builtin_amdgcn_global_load_lds((gvoid*)(uintptr_t)g, (lvoid*)(uintptr_t)l,
                                   16, 0, 0);
}

// pack 4 f32 -> 4 fp8 e4m3 bytes (OCP on gfx950)
__device__ __forceinline__ unsigned fp8x4(float a, float b, float c, float d) {
  int v = __builtin_amdgcn_cvt_pk_fp8_f32(a, b, 0, false);
  v = __builtin_amdgcn_cvt_pk_fp8_f32(c, d, v, true);
  return (unsigned)v;
}
__device__ __forceinline__ unsigned char fp8one(float a) {
  return (unsigned char)(__builtin_amdgcn_cvt_pk_fp8_f32(a, a, 0, false) & 0xff);
}

// ---------------------------------------------------------------- routing
__global__ void route_k(const int* __restrict__ eidx, int* __restrict__ row_token,
                        int* __restrict__ slot_dest, int* __restrict__ mcount,
                        float* __restrict__ out) {
  __shared__ int lh[256][NEXP];
  int tid = threadIdx.x;
  for (int i = tid; i < EC; i += 256) row_token[i] = -1;
#pragma unroll
  for (int e = 0; e < NEXP; ++e) lh[tid][e] = 0;
  __syncthreads();
  int base = tid * 32;
  for (int j = 0; j < 32; ++j) lh[tid][eidx[base + j]]++;
  __syncthreads();
  if (tid < NEXP) {
    int run = 0;
    for (int i = 0; i < 256; ++i) { int t = lh[i][tid]; lh[i][tid] = run; run += t; }
    mcount[tid] = run < CAP ? run : CAP;
    out[(size_t)NTOK * DM + tid] = (float)run;
  }
  __syncthreads();
  for (int j = 0; j < 32; ++j) {
    int t = base + j;
    int e = eidx[t];
    int r = lh[tid][e]++;
    if (r < CAP) { int dst = e * CAP + r; slot_dest[t] = dst; row_token[dst] = t >> 1; }
    else slot_dest[t] = -1;
  }
}

// ------------------------------------------------------- gather + fp32->fp8
__global__ void gather_k(const float* __restrict__ x, const int* __restrict__ row_token,
                         unsigned char* __restrict__ xg) {
  int r = blockIdx.x;
  int c = threadIdx.x * 8;
  int tok = row_token[r];
  uint2 o;
  if (tok >= 0) {
    const float* src = x + (size_t)tok * DM + c;
    float4 a = *(const float4*)src;
    float4 b = *(const float4*)(src + 4);
    o.x = fp8x4(a.x, a.y, a.z, a.w);
    o.y = fp8x4(b.x, b.y, b.z, b.w);
  } else {
    o.x = 0u; o.y = 0u;
  }
  *(uint2*)(xg + (size_t)r * DM + c) = o;
}

// --------------------------------------- fp32 [E][K][N] -> fp8 [E][N][K]
__global__ void transT_k(const float* __restrict__ w, unsigned char* __restrict__ wT) {
  __shared__ float t[64][69];
  int e = blockIdx.z;
  int n0 = blockIdx.x * 64, k0 = blockIdx.y * 64;
  const float* src = w + ((size_t)e << 22) + (size_t)k0 * DM + n0;
  unsigned char* dst = wT + ((size_t)e << 22) + (size_t)n0 * DM + k0;
  int c4 = (threadIdx.x & 15) * 4, r0 = threadIdx.x >> 4;   // 16 rows/sweep
#pragma unroll
  for (int p = 0; p < 4; ++p) {
    int r = p * 16 + r0;
    float4 v = *(const float4*)(src + (size_t)r * DM + c4);
    t[r][c4 + 0] = v.x; t[r][c4 + 1] = v.y; t[r][c4 + 2] = v.z; t[r][c4 + 3] = v.w;
  }
  __syncthreads();
  int j = threadIdx.x & 7, rr0 = threadIdx.x >> 3;          // 32 rows/sweep
#pragma unroll
  for (int q = 0; q < 2; ++q) {
    int rr = q * 32 + rr0;
    int k8 = j * 8;
    uint2 v;
    v.x = fp8x4(t[k8 + 0][rr], t[k8 + 1][rr], t[k8 + 2][rr], t[k8 + 3][rr]);
    v.y = fp8x4(t[k8 + 4][rr], t[k8 + 5][rr], t[k8 + 6][rr], t[k8 + 7][rr]);
    *(uint2*)(dst + (size_t)rr * DM + k8) = v;              // 8B stores
  }
}

// ---------------------------------------------- fused SwiGLU dual-B GEMM
// h = fp8( silu(xg@w1T) * (xg@w3T) ), one pass. R10-proven structure
// (128x128 tile, BK=128, 4 waves 2x2, single-buffer 2-barrier loop,
// mfma_scale_f32_16x16x128_f8f6f4 unit scales), with TWO B operands sharing
// the A staging: LDS 48KB (A+B1+B3), dual acc (u stays f32 into silu ->
// better accuracy than the old bf16 u round-trip; saves 84MB HBM + 1 launch).
// VGPR ~220 -> 256 alloc, 2 blocks/CU resident (measured occupancy was
// already ~2). Swizzle/staging/epilogue identical to R10 (rule #21, m89,
// m136 2-way-alias-free, XCD-chunked swizzle R5).
__global__ __launch_bounds__(256, 2)
void gemm13_k(const unsigned char* __restrict__ A0, const unsigned char* __restrict__ B1T,
              const unsigned char* __restrict__ B3T, unsigned char* __restrict__ H,
              const int* __restrict__ mcount) {
  int lbid = blockIdx.x + 16 * (blockIdx.y + 10 * blockIdx.z);
  int nb = (lbid & 7) * 160 + (lbid >> 3);
  int e = nb / 160, rem = nb % 160, mt = rem >> 4, nt = rem & 15;
  int mc = mcount[e];
  if (mt * 128 >= mc) return;

  __shared__ __align__(16) char smem[48 * 1024];
  char* lA  = smem;
  char* lB1 = smem + 16384;
  char* lB3 = smem + 32768;

  int row0 = e * CAP + mt * 128;
  const unsigned char* gA  = A0 + (size_t)row0 * DM;
  size_t boff = ((size_t)e * DM + (size_t)nt * 128) * DM;
  const unsigned char* gB1 = B1T + boff;
  const unsigned char* gB3 = B3T + boff;

  int tid = threadIdx.x, w = tid >> 6, l = tid & 63;
  int wr = w >> 1, wc = w & 1;
  int lr = l & 15, kg = l >> 4;

  int sr = tid >> 3;
  int scs = (tid & 7) ^ (sr & 7);

  f32x4 acc1[4][4], acc3[4][4];
#pragma unroll
  for (int m = 0; m < 4; ++m)
#pragma unroll
    for (int n = 0; n < 4; ++n)
#pragma unroll
      for (int j = 0; j < 4; ++j) { acc1[m][n][j] = 0.f; acc3[m][n][j] = 0.f; }

  auto rdfrag = [&](const char* lX, int R) -> i32x8 {
    int r = R + lr;
    int a0 = r * 128 + (((2 * kg + 0) ^ (r & 7)) << 4);
    int a1 = r * 128 + (((2 * kg + 1) ^ (r & 7)) << 4);
    i32x4 lo = *(const i32x4*)(lX + a0);
    i32x4 hi = *(const i32x4*)(lX + a1);
    i32x8 v;
    v[0] = lo[0]; v[1] = lo[1]; v[2] = lo[2]; v[3] = lo[3];
    v[4] = hi[0]; v[5] = hi[1]; v[6] = hi[2]; v[7] = hi[3];
    return v;
  };

#pragma unroll 1
  for (int ks = 0; ks < 16; ++ks) {          // K = 2048 = 16 * 128
#pragma unroll
    for (int s = 0; s < 4; ++s) {
      size_t goff = (size_t)(s * 32 + sr) * DM + (size_t)ks * 128 + scs * 16;
      gld16(gA  + goff, lA  + s * 4096 + w * 1024);
      gld16(gB1 + goff, lB1 + s * 4096 + w * 1024);
      gld16(gB3 + goff, lB3 + s * 4096 + w * 1024);
    }
    __syncthreads();
    i32x8 bf1[4], bf3[4];
#pragma unroll
    for (int n = 0; n < 4; ++n) bf1[n] = rdfrag(lB1, wc * 64 + n * 16);
#pragma unroll
    for (int n = 0; n < 4; ++n) bf3[n] = rdfrag(lB3, wc * 64 + n * 16);
#pragma unroll
    for (int m = 0; m < 4; ++m) {
      i32x8 af = rdfrag(lA, wr * 64 + m * 16);
#pragma unroll
      for (int n = 0; n < 4; ++n)
        acc1[m][n] = __builtin_amdgcn_mfma_scale_f32_16x16x128_f8f6f4(
            af, bf1[n], acc1[m][n], 0, 0, 0, 0x7F, 0, 0x7F);
#pragma unroll
      for (int n = 0; n < 4; ++n)
        acc3[m][n] = __builtin_amdgcn_mfma_scale_f32_16x16x128_f8f6f4(
            af, bf3[n], acc3[m][n], 0, 0, 0, 0x7F, 0, 0x7F);
    }
    __syncthreads();
  }

  // ---- epilogue: h = fp8(silu(u)*v), C/D layout m89-verified
  int rg = l >> 4;
#pragma unroll
  for (int m = 0; m < 4; ++m)
#pragma unroll
    for (int n = 0; n < 4; ++n)
#pragma unroll
      for (int j = 0; j < 4; ++j) {
        int rr = row0 + wr * 64 + m * 16 + rg * 4 + j;
        int cc = nt * 128 + wc * 64 + n * 16 + lr;
        float u = acc1[m][n][j];
        float s = u / (1.f + __expf(-u));
        H[(size_t)rr * DM + cc] = fp8one(s * acc3[m][n][j]);
      }
}

// ------------------------------------------------------------------- GEMM
// R10-proven single-B MX-fp8 GEMM (ye pass): 128x128, BK=128, 32KB LDS.
__global__ __launch_bounds__(256, 4)
void gemm_k(const unsigned char* __restrict__ A0, const unsigned char* __restrict__ BT,
            __bf16* __restrict__ C, const int* __restrict__ mcount) {
  int lbid = blockIdx.x + 16 * (blockIdx.y + 10 * blockIdx.z);
  int nb = (lbid & 7) * 160 + (lbid >> 3);
  int e = nb / 160, rem = nb % 160, mt = rem >> 4, nt = rem & 15;
  int mc = mcount[e];
  if (mt * 128 >= mc) return;

  __shared__ __align__(16) char smem[32 * 1024];
  char* lA = smem;
  char* lB = smem + 16384;

  int row0 = e * CAP + mt * 128;
  const unsigned char* gA = A0 + (size_t)row0 * DM;
  const unsigned char* gB = BT + ((size_t)e * DM + (size_t)nt * 128) * DM;

  int tid = threadIdx.x, w = tid >> 6, l = tid & 63;
  int wr = w >> 1, wc = w & 1;
  int lr = l & 15, kg = l >> 4;

  int sr = tid >> 3;
  int scs = (tid & 7) ^ (sr & 7);

  f32x4 acc[4][4];
#pragma unroll
  for (int m = 0; m < 4; ++m)
#pragma unroll
    for (int n = 0; n < 4; ++n)
#pragma unroll
      for (int j = 0; j < 4; ++j) acc[m][n][j] = 0.f;

  auto rdfrag = [&](const char* lX, int R) -> i32x8 {
    int r = R + lr;
    int a0 = r * 128 + (((2 * kg + 0) ^ (r & 7)) << 4);
    int a1 = r * 128 + (((2 * kg + 1) ^ (r & 7)) << 4);
    i32x4 lo = *(const i32x4*)(lX + a0);
    i32x4 hi = *(const i32x4*)(lX + a1);
    i32x8 v;
    v[0] = lo[0]; v[1] = lo[1]; v[2] = lo[2]; v[3] = lo[3];
    v[4] = hi[0]; v[5] = hi[1]; v[6] = hi[2]; v[7] = hi[3];
    return v;
  };

#pragma unroll 1
  for (int ks = 0; ks < 16; ++ks) {          // K = 2048 = 16 * 128
#pragma unroll
    for (int s = 0; s < 4; ++s) {
      size_t goff = (size_t)(s * 32 + sr) * DM + (size_t)ks * 128 + scs * 16;
      gld16(gA + goff, lA + s * 4096 + w * 1024);
      gld16(gB + goff, lB + s * 4096 + w * 1024);
    }
    __syncthreads();
    i32x8 bf[4];
#pragma unroll
    for (int n = 0; n < 4; ++n) bf[n] = rdfrag(lB, wc * 64 + n * 16);
#pragma unroll
    for (int m = 0; m < 4; ++m) {
      i32x8 af = rdfrag(lA, wr * 64 + m * 16);
#pragma unroll
      for (int n = 0; n < 4; ++n)
        acc[m][n] = __builtin_amdgcn_mfma_scale_f32_16x16x128_f8f6f4(
            af, bf[n], acc[m][n], 0, 0, 0, 0x7F, 0, 0x7F);
    }
    __syncthreads();
  }

  int rg = l >> 4;
#pragma unroll
  for (int m = 0; m < 4; ++m)
#pragma unroll
    for (int n = 0; n < 4; ++n)
#pragma unroll
      for (int j = 0; j < 4; ++j) {
        int rr = row0 + wr * 64 + m * 16 + rg * 4 + j;
        int cc = nt * 128 + wc * 64 + n * 16 + lr;
        C[(size_t)rr * DM + cc] = (__bf16)acc[m][n][j];
      }
}

// --------------------------------------------- combine: y[tok] = sum w * ye
__global__ void combine_k(const __bf16* __restrict__ ye, const int* __restrict__ slot_dest,
                          const float* __restrict__ ew, float* __restrict__ out) {
  int tok = blockIdx.x;
  int c = threadIdx.x * 8;
  int d0 = slot_dest[2 * tok], d1 = slot_dest[2 * tok + 1];
  float w0 = ew[2 * tok], w1 = ew[2 * tok + 1];
  float r[8];
#pragma unroll
  for (int j = 0; j < 8; ++j) r[j] = 0.f;
  if (d0 >= 0) {
    bf16x8 y0 = *(const bf16x8*)(ye + (size_t)d0 * DM + c);
#pragma unroll
    for (int j = 0; j < 8; ++j) r[j] += w0 * (float)y0[j];
  }
  if (d1 >= 0) {
    bf16x8 y1 = *(const bf16x8*)(ye + (size_t)d1 * DM + c);
#pragma unroll
    for (int j = 0; j < 8; ++j) r[j] += w1 * (float)y1[j];
  }
  float* dst = out + (size_t)tok * DM + c;
  float4 o0; o0.x = r[0]; o0.y = r[1]; o0.z = r[2]; o0.w = r[3];
  float4 o1; o1.x = r[4]; o1.y = r[5]; o1.z = r[6]; o1.w = r[7];
  *(float4*)dst = o0;
  *(float4*)(dst + 4) = o1;
}

extern "C" void kernel_launch(void* const* d_in, const int* in_sizes, int n_in,
                              void* d_out, int out_size, void* d_ws, size_t ws_size,
                              hipStream_t stream) {
  const float* x  = (const float*)d_in[0];
  const float* ew = (const float*)d_in[1];
  const int*   ei = (const int*)d_in[2];
  const float* w1 = (const float*)d_in[3];
  const float* w2 = (const float*)d_in[4];
  const float* w3 = (const float*)d_in[5];
  float* out = (float*)d_out;
  char* ws = (char*)d_ws;

  // ws: xg fp8 21MB | yeB bf16 42MB | hB fp8 21MB | wT1 33.5MB | wT3 33.5MB
  //     | routing ints   (~152MB total)
  const size_t SZ8  = (size_t)EC * DM;                  // 20,971,520
  const size_t SZ16 = 2 * SZ8;
  const size_t SZW  = (size_t)NEXP * DM * DM;           // 33,554,432
  unsigned char* xg  = (unsigned char*)ws;
  __bf16* yeB        = (__bf16*)(ws + SZ8);
  unsigned char* hB  = (unsigned char*)(ws + SZ8 + SZ16);
  unsigned char* wT1 = (unsigned char*)(ws + 2 * SZ8 + SZ16);
  unsigned char* wT3 = (unsigned char*)(ws + 2 * SZ8 + SZ16 + SZW);
  char* ints = ws + 2 * SZ8 + SZ16 + 2 * SZW;
  int* row_token = (int*)ints;
  int* slot_dest = row_token + EC;
  int* mcount    = slot_dest + NSLOT;

  dim3 tgrid(32, 32, NEXP);
  dim3 ggrid(16, 10, NEXP);                             // nt(128), mt(128), e

  route_k<<<1, 256, 0, stream>>>(ei, row_token, slot_dest, mcount, out);
  gather_k<<<EC, 256, 0, stream>>>(x, row_token, xg);

  transT_k<<<tgrid, 256, 0, stream>>>(w1, wT1);
  transT_k<<<tgrid, 256, 0, stream>>>(w3, wT3);
  gemm13_k<<<ggrid, 256, 0, stream>>>(xg, wT1, wT3, hB, mcount);  // h (fused)

  transT_k<<<tgrid, 256, 0, stream>>>(w2, wT1);
  gemm_k<<<ggrid, 256, 0, stream>>>(hB, wT1, yeB, mcount);        // ye (bf16)

  combine_k<<<NTOK, 256, 0, stream>>>(yeB, slot_dest, ew, out);
}

// Round 12
// 265.363 us; speedup vs baseline: 1.3535x; 1.1442x over previous
//
#include <hip/hip_runtime.h>
#include <cstdint>

#define NEXP 8
#define TOPK 2
#define NTOK 4096
#define NSLOT (NTOK * TOPK)   // 8192
#define CAP 1280              // expert capacity
#define DM 2048               // d_model == hidden
#define EC (NEXP * CAP)       // 10240 binned rows

typedef __bf16 bf16x8 __attribute__((ext_vector_type(8)));
typedef float  f32x4  __attribute__((ext_vector_type(4)));
typedef int    i32x4  __attribute__((ext_vector_type(4)));
typedef int    i32x8  __attribute__((ext_vector_type(8)));

typedef const void __attribute__((address_space(1))) gvoid;
typedef void __attribute__((address_space(3))) lvoid;

__device__ __forceinline__ void gld16(const void* g, void* l) {
  __builtin_amdgcn_global_load_lds((gvoid*)(uintptr_t)g, (lvoid*)(uintptr_t)l,
                                   16, 0, 0);
}

// pack 4 f32 -> 4 fp8 e4m3 bytes (OCP on gfx950)
__device__ __forceinline__ unsigned fp8x4(float a, float b, float c, float d) {
  int v = __builtin_amdgcn_cvt_pk_fp8_f32(a, b, 0, false);
  v = __builtin_amdgcn_cvt_pk_fp8_f32(c, d, v, true);
  return (unsigned)v;
}
__device__ __forceinline__ unsigned char fp8one(float a) {
  return (unsigned char)(__builtin_amdgcn_cvt_pk_fp8_f32(a, a, 0, false) & 0xff);
}

// ---------------------------------------------------------------- routing
__global__ void route_k(const int* __restrict__ eidx, int* __restrict__ row_token,
                        int* __restrict__ slot_dest, int* __restrict__ mcount,
                        float* __restrict__ out) {
  __shared__ int lh[256][NEXP];
  int tid = threadIdx.x;
  for (int i = tid; i < EC; i += 256) row_token[i] = -1;
#pragma unroll
  for (int e = 0; e < NEXP; ++e) lh[tid][e] = 0;
  __syncthreads();
  int base = tid * 32;
  for (int j = 0; j < 32; ++j) lh[tid][eidx[base + j]]++;
  __syncthreads();
  if (tid < NEXP) {
    int run = 0;
    for (int i = 0; i < 256; ++i) { int t = lh[i][tid]; lh[i][tid] = run; run += t; }
    mcount[tid] = run < CAP ? run : CAP;
    out[(size_t)NTOK * DM + tid] = (float)run;
  }
  __syncthreads();
  for (int j = 0; j < 32; ++j) {
    int t = base + j;
    int e = eidx[t];
    int r = lh[tid][e]++;
    if (r < CAP) { int dst = e * CAP + r; slot_dest[t] = dst; row_token[dst] = t >> 1; }
    else slot_dest[t] = -1;
  }
}

// ---------------------- device body: one 64x64 fp32->fp8 transpose tile
__device__ __forceinline__ void transT_tile(const float* __restrict__ w,
                                            unsigned char* __restrict__ wT,
                                            int e, int n0, int k0, char* smem) {
  float (*t)[69] = (float (*)[69])smem;
  const float* src = w + ((size_t)e << 22) + (size_t)k0 * DM + n0;
  unsigned char* dst = wT + ((size_t)e << 22) + (size_t)n0 * DM + k0;
  int c4 = (threadIdx.x & 15) * 4, r0 = threadIdx.x >> 4;   // 16 rows/sweep
#pragma unroll
  for (int p = 0; p < 4; ++p) {
    int r = p * 16 + r0;
    float4 v = *(const float4*)(src + (size_t)r * DM + c4);
    t[r][c4 + 0] = v.x; t[r][c4 + 1] = v.y; t[r][c4 + 2] = v.z; t[r][c4 + 3] = v.w;
  }
  __syncthreads();
  int j = threadIdx.x & 7, rr0 = threadIdx.x >> 3;          // 32 rows/sweep
#pragma unroll
  for (int q = 0; q < 2; ++q) {
    int rr = q * 32 + rr0;
    int k8 = j * 8;
    uint2 v;
    v.x = fp8x4(t[k8 + 0][rr], t[k8 + 1][rr], t[k8 + 2][rr], t[k8 + 3][rr]);
    v.y = fp8x4(t[k8 + 4][rr], t[k8 + 5][rr], t[k8 + 6][rr], t[k8 + 7][rr]);
    *(uint2*)(dst + (size_t)rr * DM + k8) = v;              // 8B stores
  }
}

// ------------- prep: transT(w1) + transT(w3) + gather, one HBM-bound launch
// blocks 0..8191: w1 tiles; 8192..16383: w3 tiles; 16384..17663: gather x8 rows
__global__ __launch_bounds__(256)
void prep_k(const float* __restrict__ w1, const float* __restrict__ w3,
            unsigned char* __restrict__ wT1, unsigned char* __restrict__ wT3,
            const float* __restrict__ x, const int* __restrict__ row_token,
            unsigned char* __restrict__ xg) {
  __shared__ __align__(16) char smem[64 * 69 * 4];
  int bid = blockIdx.x;
  if (bid < 16384) {
    const float* w = (bid & 8192) ? w3 : w1;
    unsigned char* wT = (bid & 8192) ? wT3 : wT1;
    int rem = bid & 8191;
    int e = rem >> 10, t = rem & 1023;
    transT_tile(w, wT, e, (t & 31) * 64, (t >> 5) * 64, smem);
  } else {
    int rbase = (bid - 16384) * 8;
    int c = threadIdx.x * 8;
#pragma unroll 1
    for (int i = 0; i < 8; ++i) {
      int r = rbase + i;
      int tok = row_token[r];
      uint2 o;
      if (tok >= 0) {
        const float* src = x + (size_t)tok * DM + c;
        float4 a = *(const float4*)src;
        float4 b = *(const float4*)(src + 4);
        o.x = fp8x4(a.x, a.y, a.z, a.w);
        o.y = fp8x4(b.x, b.y, b.z, b.w);
      } else { o.x = 0u; o.y = 0u; }
      *(uint2*)(xg + (size_t)r * DM + c) = o;
    }
  }
}

// ---------------------------------------------- fused SwiGLU dual-B GEMM
//   + concurrent transT(w2): blocks 0..1279 gemm13 (dispatched first),
//   1280..9471 transT w2 tiles (fill CU slots as gemm13 retires; gemm13 is
//   ~10% HBM so the HBM-bound transpose hides under it). Block-uniform
//   branch; LDS 48KB static (transT uses first 17.7KB).
// gemm13: h = fp8( silu(xg@w1T) * (xg@w3T) ) — R11-proven (128x128, BK=128,
// 4 waves, single-buffer 2-barrier loop, mfma_scale_f32_16x16x128 unit
// scales, dual acc, swizzle rule #21, m89 epilogue, XCD-chunked swizzle).
__global__ __launch_bounds__(256, 2)
void gemm13t_k(const unsigned char* __restrict__ A0, const unsigned char* __restrict__ B1T,
               const unsigned char* __restrict__ B3T, unsigned char* __restrict__ H,
               const int* __restrict__ mcount,
               const float* __restrict__ w2, unsigned char* __restrict__ wT2) {
  __shared__ __align__(16) char smem[48 * 1024];
  if (blockIdx.x >= 1280) {
    int rem = blockIdx.x - 1280;
    int e = rem >> 10, t = rem & 1023;
    transT_tile(w2, wT2, e, (t & 31) * 64, (t >> 5) * 64, smem);
    return;
  }
  int lbid = blockIdx.x;
  int nb = (lbid & 7) * 160 + (lbid >> 3);
  int e = nb / 160, rem = nb % 160, mt = rem >> 4, nt = rem & 15;
  int mc = mcount[e];
  if (mt * 128 >= mc) return;

  char* lA  = smem;
  char* lB1 = smem + 16384;
  char* lB3 = smem + 32768;

  int row0 = e * CAP + mt * 128;
  const unsigned char* gA  = A0 + (size_t)row0 * DM;
  size_t boff = ((size_t)e * DM + (size_t)nt * 128) * DM;
  const unsigned char* gB1 = B1T + boff;
  const unsigned char* gB3 = B3T + boff;

  int tid = threadIdx.x, w = tid >> 6, l = tid & 63;
  int wr = w >> 1, wc = w & 1;
  int lr = l & 15, kg = l >> 4;

  int sr = tid >> 3;
  int scs = (tid & 7) ^ (sr & 7);

  f32x4 acc1[4][4], acc3[4][4];
#pragma unroll
  for (int m = 0; m < 4; ++m)
#pragma unroll
    for (int n = 0; n < 4; ++n)
#pragma unroll
      for (int j = 0; j < 4; ++j) { acc1[m][n][j] = 0.f; acc3[m][n][j] = 0.f; }

  auto rdfrag = [&](const char* lX, int R) -> i32x8 {
    int r = R + lr;
    int a0 = r * 128 + (((2 * kg + 0) ^ (r & 7)) << 4);
    int a1 = r * 128 + (((2 * kg + 1) ^ (r & 7)) << 4);
    i32x4 lo = *(const i32x4*)(lX + a0);
    i32x4 hi = *(const i32x4*)(lX + a1);
    i32x8 v;
    v[0] = lo[0]; v[1] = lo[1]; v[2] = lo[2]; v[3] = lo[3];
    v[4] = hi[0]; v[5] = hi[1]; v[6] = hi[2]; v[7] = hi[3];
    return v;
  };

#pragma unroll 1
  for (int ks = 0; ks < 16; ++ks) {          // K = 2048 = 16 * 128
#pragma unroll
    for (int s = 0; s < 4; ++s) {
      size_t goff = (size_t)(s * 32 + sr) * DM + (size_t)ks * 128 + scs * 16;
      gld16(gA  + goff, lA  + s * 4096 + w * 1024);
      gld16(gB1 + goff, lB1 + s * 4096 + w * 1024);
      gld16(gB3 + goff, lB3 + s * 4096 + w * 1024);
    }
    __syncthreads();
    i32x8 bf1[4], bf3[4];
#pragma unroll
    for (int n = 0; n < 4; ++n) bf1[n] = rdfrag(lB1, wc * 64 + n * 16);
#pragma unroll
    for (int n = 0; n < 4; ++n) bf3[n] = rdfrag(lB3, wc * 64 + n * 16);
#pragma unroll
    for (int m = 0; m < 4; ++m) {
      i32x8 af = rdfrag(lA, wr * 64 + m * 16);
#pragma unroll
      for (int n = 0; n < 4; ++n)
        acc1[m][n] = __builtin_amdgcn_mfma_scale_f32_16x16x128_f8f6f4(
            af, bf1[n], acc1[m][n], 0, 0, 0, 0x7F, 0, 0x7F);
#pragma unroll
      for (int n = 0; n < 4; ++n)
        acc3[m][n] = __builtin_amdgcn_mfma_scale_f32_16x16x128_f8f6f4(
            af, bf3[n], acc3[m][n], 0, 0, 0, 0x7F, 0, 0x7F);
    }
    __syncthreads();
  }

  int rg = l >> 4;
#pragma unroll
  for (int m = 0; m < 4; ++m)
#pragma unroll
    for (int n = 0; n < 4; ++n)
#pragma unroll
      for (int j = 0; j < 4; ++j) {
        int rr = row0 + wr * 64 + m * 16 + rg * 4 + j;
        int cc = nt * 128 + wc * 64 + n * 16 + lr;
        float u = acc1[m][n][j];
        float s = u / (1.f + __expf(-u));
        H[(size_t)rr * DM + cc] = fp8one(s * acc3[m][n][j]);
      }
}

// ------------------------------------------------------------------- GEMM
// R10-proven single-B MX-fp8 GEMM (ye pass): 128x128, BK=128, 32KB LDS.
__global__ __launch_bounds__(256, 4)
void gemm_k(const unsigned char* __restrict__ A0, const unsigned char* __restrict__ BT,
            __bf16* __restrict__ C, const int* __restrict__ mcount) {
  int lbid = blockIdx.x + 16 * (blockIdx.y + 10 * blockIdx.z);
  int nb = (lbid & 7) * 160 + (lbid >> 3);
  int e = nb / 160, rem = nb % 160, mt = rem >> 4, nt = rem & 15;
  int mc = mcount[e];
  if (mt * 128 >= mc) return;

  __shared__ __align__(16) char smem[32 * 1024];
  char* lA = smem;
  char* lB = smem + 16384;

  int row0 = e * CAP + mt * 128;
  const unsigned char* gA = A0 + (size_t)row0 * DM;
  const unsigned char* gB = BT + ((size_t)e * DM + (size_t)nt * 128) * DM;

  int tid = threadIdx.x, w = tid >> 6, l = tid & 63;
  int wr = w >> 1, wc = w & 1;
  int lr = l & 15, kg = l >> 4;

  int sr = tid >> 3;
  int scs = (tid & 7) ^ (sr & 7);

  f32x4 acc[4][4];
#pragma unroll
  for (int m = 0; m < 4; ++m)
#pragma unroll
    for (int n = 0; n < 4; ++n)
#pragma unroll
      for (int j = 0; j < 4; ++j) acc[m][n][j] = 0.f;

  auto rdfrag = [&](const char* lX, int R) -> i32x8 {
    int r = R + lr;
    int a0 = r * 128 + (((2 * kg + 0) ^ (r & 7)) << 4);
    int a1 = r * 128 + (((2 * kg + 1) ^ (r & 7)) << 4);
    i32x4 lo = *(const i32x4*)(lX + a0);
    i32x4 hi = *(const i32x4*)(lX + a1);
    i32x8 v;
    v[0] = lo[0]; v[1] = lo[1]; v[2] = lo[2]; v[3] = lo[3];
    v[4] = hi[0]; v[5] = hi[1]; v[6] = hi[2]; v[7] = hi[3];
    return v;
  };

#pragma unroll 1
  for (int ks = 0; ks < 16; ++ks) {          // K = 2048 = 16 * 128
#pragma unroll
    for (int s = 0; s < 4; ++s) {
      size_t goff = (size_t)(s * 32 + sr) * DM + (size_t)ks * 128 + scs * 16;
      gld16(gA + goff, lA + s * 4096 + w * 1024);
      gld16(gB + goff, lB + s * 4096 + w * 1024);
    }
    __syncthreads();
    i32x8 bf[4];
#pragma unroll
    for (int n = 0; n < 4; ++n) bf[n] = rdfrag(lB, wc * 64 + n * 16);
#pragma unroll
    for (int m = 0; m < 4; ++m) {
      i32x8 af = rdfrag(lA, wr * 64 + m * 16);
#pragma unroll
      for (int n = 0; n < 4; ++n)
        acc[m][n] = __builtin_amdgcn_mfma_scale_f32_16x16x128_f8f6f4(
            af, bf[n], acc[m][n], 0, 0, 0, 0x7F, 0, 0x7F);
    }
    __syncthreads();
  }

  int rg = l >> 4;
#pragma unroll
  for (int m = 0; m < 4; ++m)
#pragma unroll
    for (int n = 0; n < 4; ++n)
#pragma unroll
      for (int j = 0; j < 4; ++j) {
        int rr = row0 + wr * 64 + m * 16 + rg * 4 + j;
        int cc = nt * 128 + wc * 64 + n * 16 + lr;
        C[(size_t)rr * DM + cc] = (__bf16)acc[m][n][j];
      }
}

// --------------------------------------------- combine: y[tok] = sum w * ye
__global__ void combine_k(const __bf16* __restrict__ ye, const int* __restrict__ slot_dest,
                          const float* __restrict__ ew, float* __restrict__ out) {
  int tok = blockIdx.x;
  int c = threadIdx.x * 8;
  int d0 = slot_dest[2 * tok], d1 = slot_dest[2 * tok + 1];
  float w0 = ew[2 * tok], w1 = ew[2 * tok + 1];
  float r[8];
#pragma unroll
  for (int j = 0; j < 8; ++j) r[j] = 0.f;
  if (d0 >= 0) {
    bf16x8 y0 = *(const bf16x8*)(ye + (size_t)d0 * DM + c);
#pragma unroll
    for (int j = 0; j < 8; ++j) r[j] += w0 * (float)y0[j];
  }
  if (d1 >= 0) {
    bf16x8 y1 = *(const bf16x8*)(ye + (size_t)d1 * DM + c);
#pragma unroll
    for (int j = 0; j < 8; ++j) r[j] += w1 * (float)y1[j];
  }
  float* dst = out + (size_t)tok * DM + c;
  float4 o0; o0.x = r[0]; o0.y = r[1]; o0.z = r[2]; o0.w = r[3];
  float4 o1; o1.x = r[4]; o1.y = r[5]; o1.z = r[6]; o1.w = r[7];
  *(float4*)dst = o0;
  *(float4*)(dst + 4) = o1;
}

extern "C" void kernel_launch(void* const* d_in, const int* in_sizes, int n_in,
                              void* d_out, int out_size, void* d_ws, size_t ws_size,
                              hipStream_t stream) {
  const float* x  = (const float*)d_in[0];
  const float* ew = (const float*)d_in[1];
  const int*   ei = (const int*)d_in[2];
  const float* w1 = (const float*)d_in[3];
  const float* w2 = (const float*)d_in[4];
  const float* w3 = (const float*)d_in[5];
  float* out = (float*)d_out;
  char* ws = (char*)d_ws;

  // ws: xg fp8 21MB | yeB bf16 42MB | hB fp8 21MB | wT1 | wT3 | wT2 (33.5MB
  //     each) | routing ints   (~185MB total)
  const size_t SZ8  = (size_t)EC * DM;                  // 20,971,520
  const size_t SZ16 = 2 * SZ8;
  const size_t SZW  = (size_t)NEXP * DM * DM;           // 33,554,432
  unsigned char* xg  = (unsigned char*)ws;
  __bf16* yeB        = (__bf16*)(ws + SZ8);
  unsigned char* hB  = (unsigned char*)(ws + SZ8 + SZ16);
  unsigned char* wT1 = (unsigned char*)(ws + 2 * SZ8 + SZ16);
  unsigned char* wT3 = (unsigned char*)(ws + 2 * SZ8 + SZ16 + SZW);
  unsigned char* wT2 = (unsigned char*)(ws + 2 * SZ8 + SZ16 + 2 * SZW);
  char* ints = ws + 2 * SZ8 + SZ16 + 3 * SZW;
  int* row_token = (int*)ints;
  int* slot_dest = row_token + EC;
  int* mcount    = slot_dest + NSLOT;

  dim3 ggrid(16, 10, NEXP);                             // ye gemm grid

  route_k<<<1, 256, 0, stream>>>(ei, row_token, slot_dest, mcount, out);
  prep_k<<<17664, 256, 0, stream>>>(w1, w3, wT1, wT3, x, row_token, xg);
  gemm13t_k<<<9472, 256, 0, stream>>>(xg, wT1, wT3, hB, mcount, w2, wT2); // h + w2 prep
  gemm_k<<<ggrid, 256, 0, stream>>>(hB, wT2, yeB, mcount);                // ye (bf16)
  combine_k<<<NTOK, 256, 0, stream>>>(yeB, slot_dest, ew, out);
}